// Round 1
// 83615.692 us; speedup vs baseline: 1.7773x; 1.7773x over previous
//
#include <hip/hip_runtime.h>
#include <hip/hip_bf16.h>

// BidRnn: B=128, T=1024, H=512. Bidirectional GRU + scheduled-sampling predictor.
//
// Round 2: weight-stationary cross-WG GEMM.
// Old structure (149 ms): 256 WGs x (batch,dir), each re-streaming the same 4 MB
// of fp32 weights EVERY step -> ~1 TB of L2/LLC traffic, 1 wave/SIMD, 12-op
// serial shfl chains; VALUBusy 8.6% == pure issue cycles -> 91% latency stall.
//
// New structure:
//  * Each of 256 WGs pins a 16-column slice of [w_hh ; p_w1] (32 KB fp32) in
//    LDS, read from global exactly ONCE per launch.
//  * Phase A (per step): WG computes S[dir][b][col] = sum_k H[dir][k][b]*W[col][k]
//    for ALL 128 batches. H is stored k-major so b vectorizes into float4 loads;
//    8 independent accumulators/thread give ILP instead of occupancy.
//  * grid barrier; Phase B: WG (dir,b) finishes predictor + GRU pointwise,
//    writes h_t into H_T (k-major) and the output; grid barrier.
// Global traffic/step ~4.6 MB (was ~1 GB). Weights: 7 MB total (was 1 TB).
//
// Grid sync: custom monotonic atomic-counter barrier in d_ws (device-scope
// atomics + __threadfence release/acquire for cross-XCD L2 visibility).
// Counter is re-zeroed by the probe kernel every launch -> graph-replay safe.
// 256 WGs x 256 thr, ~56 KB LDS -> one WG per CU, all co-resident.
// Workspace needed: 512 B header + 512 KB H_T + 2 MB S = ~2.63 MB of d_ws.

#define T_STEPS 1024
#define H_DIM   512
#define NBLK    256

__device__ __forceinline__ float bf2f(unsigned int u){
  union { unsigned int i; float f; } v; v.i = u << 16; return v.f;
}
__device__ __forceinline__ float ldw(const float* p){ return *p; }
__device__ __forceinline__ float ldw(const __hip_bfloat16* p){
  unsigned short s = *(const unsigned short*)p; return bf2f((unsigned int)s);
}
__device__ __forceinline__ void stw(float* p, float v){ *p = v; }
__device__ __forceinline__ void stw(__hip_bfloat16* p, float v){ *p = __float2bfloat16(v); }

// ---------------------------------------------------------------------------
// Probe: classify mask encoding and float dtype (unchanged from round 1), and
// zero the grid-barrier counter (codes[2], codes[3]) so every launch / graph
// replay starts with a clean barrier state.
// ---------------------------------------------------------------------------
__global__ void probe_kernel(const unsigned int* __restrict__ mw,
                             const unsigned int* __restrict__ ww,
                             int* __restrict__ codes){
  __shared__ unsigned int fl[5];
  if(threadIdx.x < 5) fl[threadIdx.x] = 0u;
  __syncthreads();
  unsigned int l0=0,l1=0,l2=0,l3=0,l4=0;
  for(int i=threadIdx.x; i<32768; i+=256){
    const unsigned int w = mw[i];
    #pragma unroll
    for(int bb=0;bb<4;bb++){
      const unsigned int by = (w >> (8*bb)) & 0xFFu;
      if(by > 1u) l0 = 1u;                 // u8 violation
      if(bb!=0 && by==1u) l1 = 1u;         // u8 evidence
    }
    const unsigned int hlo = w & 0xFFFFu, hhi = w >> 16;
    if(!(hlo==0u || hlo==0x3F80u) || !(hhi==0u || hhi==0x3F80u)) l2 = 1u;
    if(hlo == 0x3F80u) l3 = 1u;            // bf16 evidence
  }
  for(int i=threadIdx.x; i<768; i+=256){
    const unsigned int w = ww[i];
    const unsigned int hlo = w & 0xFFFFu;
    if(hlo != 0u && ((hlo>>7)&0xFFu) >= 128u) l4 = 1u;  // fp32 evidence
  }
  if(l0) atomicOr(&fl[0],1u);
  if(l1) atomicOr(&fl[1],1u);
  if(l2) atomicOr(&fl[2],1u);
  if(l3) atomicOr(&fl[3],1u);
  if(l4) atomicOr(&fl[4],1u);
  __syncthreads();
  if(threadIdx.x==0){
    int mcode;
    if(!fl[0] && fl[1])      mcode = 1;   // byte mask
    else if(!fl[2] && fl[3]) mcode = 2;   // bf16 mask
    else                     mcode = 4;   // 4-byte mask
    codes[0] = mcode;
    codes[1] = fl[4] ? 1 : 0;
    codes[2] = 0;                          // grid-barrier arrival counter
    codes[3] = 0;                          // (spare)
  }
}

// ---------------------------------------------------------------------------
// Monotonic grid barrier. cnt starts at 0 each launch (probe zeroes it); each
// call adds NBLK to the per-block target. Release: __threadfence() writes back
// dirty L2 (cross-XCD visibility). Acquire: __threadfence() invalidates L1/L2
// so post-barrier reads see remote writes. Only thread 0 spins (agent-scope
// atomic load bypasses L1/L2-local); other waves sleep at s_barrier.
// ---------------------------------------------------------------------------
__device__ __forceinline__ void grid_bar(int* cnt, int& nbar){
  __syncthreads();                                   // drains this WG's vmem
  if(threadIdx.x==0){
    __threadfence();                                 // release
    __hip_atomic_fetch_add(cnt, 1, __ATOMIC_RELAXED, __HIP_MEMORY_SCOPE_AGENT);
    nbar += NBLK;
    while(__hip_atomic_load(cnt, __ATOMIC_RELAXED, __HIP_MEMORY_SCOPE_AGENT) < nbar)
      __builtin_amdgcn_s_sleep(1);
    __threadfence();                                 // acquire
  }
  __syncthreads();
}

// ---------------------------------------------------------------------------
// Main body.
// A-role: WG w owns 16 columns of the combined per-dir weight matrix
//   cols [0,1536) = w_hh rows, cols [1536,2048) = p_w1 rows (predictor).
//   dirA = w>>7, colbase = (w&127)*16. Slice pinned in LDS (padded rows: 516).
// B-role: WG w owns (dir = w>>7, b = w&127): predictor scalar + GRU update.
// H_T layout: [dir][k=0..511][b=0..127] (k-major -> phase A float4 on b).
// S   layout: [dir][b][c=0..2047]       (c-contig  -> phase B coalesced).
// ---------------------------------------------------------------------------
template<typename WT, typename OT>
__device__ void body(const void* xv, const void* mkv,
                     const void* wfih, const void* wfhh, const void* bfih, const void* bfhh,
                     const void* wbih, const void* wbhh, const void* bbih, const void* bbhh,
                     const void* pw1v, const void* pb1v, const void* pw2v, const void* pb2v,
                     int mcode, OT* __restrict__ out, float* H_T, float* S, int* cnt,
                     float* wsl, float* wih, float* bih, float* bhh,
                     float* pb1c, float* pw2c, float* red, float* xsh)
{
  const int w   = (int)blockIdx.x;
  const int tid = (int)threadIdx.x;
  const int dir = w >> 7;
  const int b   = w & 127;
  const int colbase = (w & 127) * 16;

  const WT* x  = (const WT*)xv;
  const unsigned char* mk = (const unsigned char*)mkv;

  // --- one-time staging ---------------------------------------------------
  const WT* whhA  = (const WT*)(dir ? wbhh : wfhh);
  const WT* wrows = (colbase < 1536)
                  ? (whhA + (size_t)colbase * H_DIM)
                  : ((const WT*)pw1v + (size_t)(colbase - 1536) * H_DIM);
  for(int idx = tid; idx < 16*512; idx += 256){
    const int r = idx >> 9, k = idx & 511;
    wsl[r*516 + k] = ldw(wrows + (size_t)r*512 + k);   // +4 pad: conflict-free
  }
  const WT* wihp = (const WT*)(dir ? wbih : wfih);
  const WT* bihp = (const WT*)(dir ? bbih : bfih);
  const WT* bhhp = (const WT*)(dir ? bbhh : bfhh);
  for(int i=tid;i<1536;i+=256){ wih[i]=ldw(wihp+i); bih[i]=ldw(bihp+i); bhh[i]=ldw(bhhp+i); }
  for(int i=tid;i<512;i+=256){ pb1c[i]=ldw((const WT*)pb1v+i); pw2c[i]=ldw((const WT*)pw2v+i); }
  const float pb2s = ldw((const WT*)pb2v);

  // zero H_T (h0 = 0): each WG zeroes its 512-float stripe
  H_T[w*512 + tid]       = 0.f;
  H_T[w*512 + 256 + tid] = 0.f;

  int nbar = 0;
  grid_bar(cnt, nbar);                       // barrier 0: H_T zeroed everywhere

  // --- per-role constants --------------------------------------------------
  const int   cA  = tid >> 5;                // 0..7  -> cols cA and cA+8
  const int   bg  = tid & 31;                // 0..31 -> batches bg*4..bg*4+3
  const int   b0  = bg * 4;
  const float* HbA = H_T + dir*65536;        // [k][b]
  const float* wr0 = wsl + cA*516;
  const float* wr1 = wsl + (cA+8)*516;
  float*      SbA = S + (size_t)dir*128*2048 + colbase;

  const int j1 = tid, j2 = tid + 256;
  const float* Sb2 = S + ((size_t)dir*128 + b)*2048;

  float hp1 = 0.f, hp2 = 0.f;                // h_{t-1}[j1], h_{t-1}[j2]

  for(int t=0; t<T_STEPS; t++){
    // ======== Phase A: S = H @ Wslice^T (all 128 batches) ========
    float aA0=0.f,aA1=0.f,aA2=0.f,aA3=0.f;   // col cA,  batches b0..b0+3
    float aB0=0.f,aB1=0.f,aB2=0.f,aB3=0.f;   // col cA+8
    for(int k=0;k<512;k+=4){
      const float4 w0 = *(const float4*)(wr0 + k);
      const float4 w1 = *(const float4*)(wr1 + k);
      const float* hp = HbA + k*128 + b0;
      const float4 h0 = *(const float4*)(hp);
      const float4 h1 = *(const float4*)(hp + 128);
      const float4 h2 = *(const float4*)(hp + 256);
      const float4 h3 = *(const float4*)(hp + 384);
      aA0=fmaf(w0.x,h0.x,aA0); aA1=fmaf(w0.x,h0.y,aA1); aA2=fmaf(w0.x,h0.z,aA2); aA3=fmaf(w0.x,h0.w,aA3);
      aB0=fmaf(w1.x,h0.x,aB0); aB1=fmaf(w1.x,h0.y,aB1); aB2=fmaf(w1.x,h0.z,aB2); aB3=fmaf(w1.x,h0.w,aB3);
      aA0=fmaf(w0.y,h1.x,aA0); aA1=fmaf(w0.y,h1.y,aA1); aA2=fmaf(w0.y,h1.z,aA2); aA3=fmaf(w0.y,h1.w,aA3);
      aB0=fmaf(w1.y,h1.x,aB0); aB1=fmaf(w1.y,h1.y,aB1); aB2=fmaf(w1.y,h1.z,aB2); aB3=fmaf(w1.y,h1.w,aB3);
      aA0=fmaf(w0.z,h2.x,aA0); aA1=fmaf(w0.z,h2.y,aA1); aA2=fmaf(w0.z,h2.z,aA2); aA3=fmaf(w0.z,h2.w,aA3);
      aB0=fmaf(w1.z,h2.x,aB0); aB1=fmaf(w1.z,h2.y,aB1); aB2=fmaf(w1.z,h2.z,aB2); aB3=fmaf(w1.z,h2.w,aB3);
      aA0=fmaf(w0.w,h3.x,aA0); aA1=fmaf(w0.w,h3.y,aA1); aA2=fmaf(w0.w,h3.z,aA2); aA3=fmaf(w0.w,h3.w,aA3);
      aB0=fmaf(w1.w,h3.x,aB0); aB1=fmaf(w1.w,h3.y,aB1); aB2=fmaf(w1.w,h3.z,aB2); aB3=fmaf(w1.w,h3.w,aB3);
    }
    {
      float* sp = SbA + (size_t)b0*2048 + cA;
      sp[0]      = aA0;  sp[8]      = aB0;
      sp[2048]   = aA1;  sp[2048+8] = aB1;
      sp[4096]   = aA2;  sp[4096+8] = aB2;
      sp[6144]   = aA3;  sp[6144+8] = aB3;
    }
    grid_bar(cnt, nbar);                     // S complete, globally visible

    // ======== Phase B: predictor + GRU pointwise for (dir, b) ========
    const int ts = dir ? (T_STEPS-1-t) : t;
    // gate pre-activations (issue loads early; coalesced 1KB chunks)
    const float s_r1 = Sb2[j1],      s_r2 = Sb2[j2];
    const float s_z1 = Sb2[512+j1],  s_z2 = Sb2[512+j2];
    const float s_n1 = Sb2[1024+j1], s_n2 = Sb2[1024+j2];
    const float sp1  = Sb2[1536+j1], sp2  = Sb2[1536+j2];

    // predictor scalar: tanh( relu(S_p + pb1) . pw2 + pb2 )
    {
      float u1 = sp1 + pb1c[j1]; u1 = u1 > 0.f ? u1 : 0.f;
      float u2 = sp2 + pb1c[j2]; u2 = u2 > 0.f ? u2 : 0.f;
      float v = fmaf(u1, pw2c[j1], u2*pw2c[j2]);
      #pragma unroll
      for(int off=32; off; off>>=1) v += __shfl_xor(v, off, 64);
      if((tid & 63)==0) red[tid>>6] = v;
    }
    __syncthreads();
    if(tid==0){
      const size_t idx = (size_t)b*T_STEPS + ts;
      bool mfl;
      if(mcode==1)      mfl = mk[idx] != 0;
      else if(mcode==2) mfl = ((const unsigned short*)mk)[idx] != 0;
      else              mfl = ((const unsigned int*)mk)[idx]  != 0;
      const float xraw = ldw(x + idx);
      const float xp = tanhf(red[0]+red[1]+red[2]+red[3] + pb2s);
      xsh[0] = mfl ? xp : xraw;
    }
    __syncthreads();
    const float xin = xsh[0];

    // GRU gates for this thread's two h indices
    const float gr1 = s_r1 + bhh[j1];
    const float gz1 = s_z1 + bhh[512+j1];
    const float gn1 = s_n1 + bhh[1024+j1];
    const float ir1 = fmaf(xin, wih[j1],       bih[j1]);
    const float iz1 = fmaf(xin, wih[512+j1],   bih[512+j1]);
    const float in1 = fmaf(xin, wih[1024+j1],  bih[1024+j1]);
    const float r1  = 1.f/(1.f+__expf(-(ir1+gr1)));
    const float z1  = 1.f/(1.f+__expf(-(iz1+gz1)));
    const float n1  = tanhf(fmaf(r1, gn1, in1));
    const float hn1 = (1.f-z1)*n1 + z1*hp1;

    const float gr2 = s_r2 + bhh[j2];
    const float gz2 = s_z2 + bhh[512+j2];
    const float gn2 = s_n2 + bhh[1024+j2];
    const float ir2 = fmaf(xin, wih[j2],       bih[j2]);
    const float iz2 = fmaf(xin, wih[512+j2],   bih[512+j2]);
    const float in2 = fmaf(xin, wih[1024+j2],  bih[1024+j2]);
    const float r2  = 1.f/(1.f+__expf(-(ir2+gr2)));
    const float z2  = 1.f/(1.f+__expf(-(iz2+gz2)));
    const float n2  = tanhf(fmaf(r2, gn2, in2));
    const float hn2 = (1.f-z2)*n2 + z2*hp2;

    hp1 = hn1; hp2 = hn2;

    // stores: output (coalesced) + H_T k-major (strided 4B, 2/thread)
    {
      OT* op = out + ((size_t)b*T_STEPS + ts)*(2*H_DIM) + (size_t)dir*H_DIM;
      stw(op + j1, hn1); stw(op + j2, hn2);
      float* Ht = H_T + dir*65536;
      Ht[j1*128 + b] = hn1;
      Ht[j2*128 + b] = hn2;
    }
    grid_bar(cnt, nbar);                     // h_t visible for next phase A
  }
}

__global__ __launch_bounds__(256, 1)
void rnn_kernel(const void* i0,const void* i1,const void* i2,const void* i3,
                const void* i4,const void* i5,const void* i6,const void* i7,
                const void* i8,const void* i9,const void* i10,const void* i11,
                const void* i12,const void* i13, int* codes, void* out, float* ws)
{
  __shared__ float wsl[16*516];              // 33.0 KB weight slice (padded)
  __shared__ float wih[1536], bih[1536], bhh[1536];
  __shared__ float pb1c[512], pw2c[512];
  __shared__ float red[4];
  __shared__ float xsh[1];

  float* H_T = ws;                           // [2][512][128] = 512 KB
  float* S   = ws + 2*512*128;               // [2][128][2048] = 2 MB
  int*   cnt = codes + 2;

  if(codes[1]==0)
    body<__hip_bfloat16,__hip_bfloat16>(i0,i1,i2,i3,i4,i5,i6,i7,i8,i9,i10,i11,i12,i13,
        codes[0], (__hip_bfloat16*)out, H_T, S, cnt,
        wsl, wih, bih, bhh, pb1c, pw2c, red, xsh);
  else
    body<float,float>(i0,i1,i2,i3,i4,i5,i6,i7,i8,i9,i10,i11,i12,i13,
        codes[0], (float*)out, H_T, S, cnt,
        wsl, wih, bih, bhh, pb1c, pw2c, red, xsh);
}

extern "C" void kernel_launch(void* const* d_in, const int* in_sizes, int n_in,
                              void* d_out, int out_size, void* d_ws, size_t ws_size,
                              hipStream_t stream)
{
  (void)in_sizes; (void)n_in; (void)out_size; (void)ws_size;
  int*   codes = (int*)d_ws;
  float* ws    = (float*)((char*)d_ws + 512);   // 16B-aligned work area
  probe_kernel<<<1, 256, 0, stream>>>((const unsigned int*)d_in[1],
                                      (const unsigned int*)d_in[2], codes);
  rnn_kernel<<<NBLK, 256, 0, stream>>>(d_in[0],d_in[1],d_in[2],d_in[3],d_in[4],
                                       d_in[5],d_in[6],d_in[7],d_in[8],d_in[9],
                                       d_in[10],d_in[11],d_in[12],d_in[13],
                                       codes, d_out, ws);
}

// Round 2
// 82525.116 us; speedup vs baseline: 1.8008x; 1.0132x over previous
//
#include <hip/hip_runtime.h>
#include <hip/hip_bf16.h>

// BidRnn: B=128, T=1024, H=512. Bidirectional GRU + scheduled-sampling predictor.
//
// Round 3: weight-stationary cross-WG GEMM (round 2 structure) with the
// synchronization machinery rebuilt. Round-2 post-mortem: VALUBusy 5.6%,
// ~70 of 81.6 us/step was barrier+fence cost:
//   (a) 256 serialized far-atomic RMWs on ONE line per barrier, racing 256
//       spin-polling waves on the same line (every poll = LLC round trip);
//   (b) __threadfence (acq_rel) -> full L2 wb + inv per WG per barrier;
//   (c) H_T k-major scatter stores: 4B-dirty/64B-line x16 write-amp flushed
//       by wbl2 every phase (the measured 8 MB/step WRITE_SIZE).
// Fixes:
//   1. Tree barrier: 16 leaf counters (separate lines) + root + 16 broadcast
//      epoch-flag copies. Relaxed agent atomics + explicit one-sided fences
//      (__builtin_amdgcn_fence RELEASE / ACQUIRE, "agent").
//   2. H stored b-major [dir][b][k]: phase B writes coalesced (no write-amp);
//      phase A reads 4 rows x float4 (3/4 of touches are L2 hits).
//   3. Phase-B per-thread constants in registers (no LDS staging, 33 KB LDS).
// Every S/H/out cacheline has a single writer WG -> no wbl2 merge hazards.
// Workspace: 8 KB header (codes + barrier tree) + 512 KB H + 2 MB S.

#define T_STEPS 1024
#define H_DIM   512
#define NBLK    256

__device__ __forceinline__ float bf2f(unsigned int u){
  union { unsigned int i; float f; } v; v.i = u << 16; return v.f;
}
__device__ __forceinline__ float ldw(const float* p){ return *p; }
__device__ __forceinline__ float ldw(const __hip_bfloat16* p){
  unsigned short s = *(const unsigned short*)p; return bf2f((unsigned int)s);
}
__device__ __forceinline__ void stw(float* p, float v){ *p = v; }
__device__ __forceinline__ void stw(__hip_bfloat16* p, float v){ *p = __float2bfloat16(v); }

// ---------------------------------------------------------------------------
// Probe: classify mask encoding and float dtype (unchanged), and zero the
// barrier tree region (ints [256, 2048) of the workspace header) so every
// launch / graph replay starts with clean monotonic counters.
// ---------------------------------------------------------------------------
__global__ void probe_kernel(const unsigned int* __restrict__ mw,
                             const unsigned int* __restrict__ ww,
                             int* __restrict__ codes){
  __shared__ unsigned int fl[5];
  if(threadIdx.x < 5) fl[threadIdx.x] = 0u;
  __syncthreads();
  unsigned int l0=0,l1=0,l2=0,l3=0,l4=0;
  for(int i=threadIdx.x; i<32768; i+=256){
    const unsigned int w = mw[i];
    #pragma unroll
    for(int bb=0;bb<4;bb++){
      const unsigned int by = (w >> (8*bb)) & 0xFFu;
      if(by > 1u) l0 = 1u;                 // u8 violation
      if(bb!=0 && by==1u) l1 = 1u;         // u8 evidence
    }
    const unsigned int hlo = w & 0xFFFFu, hhi = w >> 16;
    if(!(hlo==0u || hlo==0x3F80u) || !(hhi==0u || hhi==0x3F80u)) l2 = 1u;
    if(hlo == 0x3F80u) l3 = 1u;            // bf16 evidence
  }
  for(int i=threadIdx.x; i<768; i+=256){
    const unsigned int w = ww[i];
    const unsigned int hlo = w & 0xFFFFu;
    if(hlo != 0u && ((hlo>>7)&0xFFu) >= 128u) l4 = 1u;  // fp32 evidence
  }
  if(l0) atomicOr(&fl[0],1u);
  if(l1) atomicOr(&fl[1],1u);
  if(l2) atomicOr(&fl[2],1u);
  if(l3) atomicOr(&fl[3],1u);
  if(l4) atomicOr(&fl[4],1u);
  // zero barrier tree (leaf[16] + root + 16 flag copies, 128B-spaced lines)
  for(int i=threadIdx.x; i<1792; i+=256) codes[256+i] = 0;
  __syncthreads();
  if(threadIdx.x==0){
    int mcode;
    if(!fl[0] && fl[1])      mcode = 1;   // byte mask
    else if(!fl[2] && fl[3]) mcode = 2;   // bf16 mask
    else                     mcode = 4;   // 4-byte mask
    codes[0] = mcode;
    codes[1] = fl[4] ? 1 : 0;
  }
}

// ---------------------------------------------------------------------------
// Two-level monotonic grid barrier with broadcast epoch flags.
// bar layout (ints, 32-int = 128B spacing): leaf g at bar[g*32] (g<16),
// root at bar[16*32], flag copy g at bar[(18+g)*32].
// Epoch ep = 1,2,3,... Leaf g reaches ep*16 adds at epoch ep; its last
// arriver bumps root; root's 16th arriver broadcasts ep to all 16 flags.
// Spinners poll only their group's flag copy (read-only, 16 pollers/line).
// Release fence (wbl2) before arrival publishes this WG's plain stores
// (entry __syncthreads already drained every wave's vmcnt, so all 4 waves'
// stores are in this XCD's L2 before thread 0 flushes it); acquire fence
// (inv) after exit makes remote XCDs' published stores readable.
// ---------------------------------------------------------------------------
__device__ __forceinline__ void grid_barrier(int* bar, int ep, int grp){
  __syncthreads();                                  // all 4 waves' vmem drained
  if(threadIdx.x==0){
    __builtin_amdgcn_fence(__ATOMIC_RELEASE, "agent");   // wbl2: publish stores
    const int old = __hip_atomic_fetch_add(bar + grp*32, 1,
                      __ATOMIC_RELAXED, __HIP_MEMORY_SCOPE_AGENT);
    if(old == ep*16 - 1){                           // last of my 16-WG group
      const int r2 = __hip_atomic_fetch_add(bar + 16*32, 1,
                      __ATOMIC_RELAXED, __HIP_MEMORY_SCOPE_AGENT);
      if(r2 == ep*16 - 1){                          // last group overall
        #pragma unroll
        for(int g=0; g<16; ++g)
          __hip_atomic_store(bar + (18+g)*32, ep,
                             __ATOMIC_RELAXED, __HIP_MEMORY_SCOPE_AGENT);
      }
    }
    int* myflag = bar + (18+grp)*32;
    while(__hip_atomic_load(myflag, __ATOMIC_RELAXED,
                            __HIP_MEMORY_SCOPE_AGENT) < ep)
      __builtin_amdgcn_s_sleep(4);
    __builtin_amdgcn_fence(__ATOMIC_ACQUIRE, "agent");   // inv: see remote stores
  }
  __syncthreads();
}

// ---------------------------------------------------------------------------
// Main body.
// A-role: WG w owns 16 columns of the per-dir combined weight matrix
//   cols [0,1536) = w_hh rows, [1536,2048) = p_w1 rows. Slice in LDS.
// B-role: WG w owns (dir=w>>7, b=w&127): predictor scalar + GRU pointwise.
// H layout: [dir][b][k]  (b-major: phase-B writes coalesced, phase-A reads
//           4 rows x float4 with L2 reuse; single writer per 64B line).
// S layout: [dir][b][c]  (c-contig; 16-col groups are 64B-line aligned ->
//           single writer per line; phase-B reads coalesced).
// ---------------------------------------------------------------------------
template<typename WT, typename OT>
__device__ void body(const void* xv, const void* mkv,
                     const void* wfih, const void* wfhh, const void* bfih, const void* bfhh,
                     const void* wbih, const void* wbhh, const void* bbih, const void* bbhh,
                     const void* pw1v, const void* pb1v, const void* pw2v, const void* pb2v,
                     int mcode, OT* __restrict__ out, float* H_B, float* S, int* bar,
                     float* wsl, float* red, float* xsh)
{
  const int w   = (int)blockIdx.x;
  const int tid = (int)threadIdx.x;
  const int dir = w >> 7;
  const int b   = w & 127;
  const int grp = w & 15;
  const int colbase = (w & 127) * 16;

  const WT* x  = (const WT*)xv;
  const unsigned char* mk = (const unsigned char*)mkv;

  // --- one-time staging: weight slice into LDS ----------------------------
  const WT* whhA  = (const WT*)(dir ? wbhh : wfhh);
  const WT* wrows = (colbase < 1536)
                  ? (whhA + (size_t)colbase * H_DIM)
                  : ((const WT*)pw1v + (size_t)(colbase - 1536) * H_DIM);
  for(int idx = tid; idx < 16*512; idx += 256){
    const int r = idx >> 9, k = idx & 511;
    wsl[r*516 + k] = ldw(wrows + (size_t)r*512 + k);   // +4 pad
  }

  // --- phase-B constants into registers (fixed per thread) ----------------
  const WT* wihp = (const WT*)(dir ? wbih : wfih);
  const WT* bihp = (const WT*)(dir ? bbih : bfih);
  const WT* bhhp = (const WT*)(dir ? bbhh : bfhh);
  const int j1 = tid, j2 = tid + 256;
  const float wi_r1=ldw(wihp+j1),      wi_r2=ldw(wihp+j2);
  const float wi_z1=ldw(wihp+512+j1),  wi_z2=ldw(wihp+512+j2);
  const float wi_n1=ldw(wihp+1024+j1), wi_n2=ldw(wihp+1024+j2);
  const float bi_r1=ldw(bihp+j1),      bi_r2=ldw(bihp+j2);
  const float bi_z1=ldw(bihp+512+j1),  bi_z2=ldw(bihp+512+j2);
  const float bi_n1=ldw(bihp+1024+j1), bi_n2=ldw(bihp+1024+j2);
  const float bh_r1=ldw(bhhp+j1),      bh_r2=ldw(bhhp+j2);
  const float bh_z1=ldw(bhhp+512+j1),  bh_z2=ldw(bhhp+512+j2);
  const float bh_n1=ldw(bhhp+1024+j1), bh_n2=ldw(bhhp+1024+j2);
  const float pb11=ldw((const WT*)pb1v+j1), pb12=ldw((const WT*)pb1v+j2);
  const float pw21=ldw((const WT*)pw2v+j1), pw22=ldw((const WT*)pw2v+j2);
  const float pb2s=ldw((const WT*)pb2v);

  // zero this WG's H row (h0 = 0): coalesced
  {
    float* hrow = H_B + ((size_t)dir*128 + b)*512;
    hrow[tid] = 0.f; hrow[tid+256] = 0.f;
  }
  int ep = 0;
  grid_barrier(bar, ++ep, grp);              // H zeroed everywhere

  // --- per-role constants --------------------------------------------------
  const int   cA  = tid >> 5;                // 0..7 -> cols cA, cA+8
  const int   bg  = tid & 31;                // batch quad
  const int   b0  = bg * 4;
  const float* wr0 = wsl + cA*516;
  const float* wr1 = wsl + (cA+8)*516;
  const float* HbA = H_B + (size_t)dir*128*512;
  const float* h0p = HbA + (size_t)(b0+0)*512;
  const float* h1p = HbA + (size_t)(b0+1)*512;
  const float* h2p = HbA + (size_t)(b0+2)*512;
  const float* h3p = HbA + (size_t)(b0+3)*512;
  float*      SbA = S + (size_t)dir*128*2048 + colbase;
  const float* Sb2 = S + ((size_t)dir*128 + b)*2048;

  float hp1 = 0.f, hp2 = 0.f;                // h_{t-1}[j1], h_{t-1}[j2]

  for(int t=0; t<T_STEPS; t++){
    // ======== Phase A: S[b'][c] = dot(H[b'], W[c]) for 8 (c,b') pairs ====
    float aA0=0.f,aA1=0.f,aA2=0.f,aA3=0.f;   // col cA,   batches b0..b0+3
    float aB0=0.f,aB1=0.f,aB2=0.f,aB3=0.f;   // col cA+8
    for(int k=0;k<512;k+=4){
      const float4 w0 = *(const float4*)(wr0 + k);
      const float4 w1 = *(const float4*)(wr1 + k);
      const float4 h0 = *(const float4*)(h0p + k);
      const float4 h1 = *(const float4*)(h1p + k);
      const float4 h2 = *(const float4*)(h2p + k);
      const float4 h3 = *(const float4*)(h3p + k);
      aA0=fmaf(w0.x,h0.x,aA0); aA0=fmaf(w0.y,h0.y,aA0); aA0=fmaf(w0.z,h0.z,aA0); aA0=fmaf(w0.w,h0.w,aA0);
      aA1=fmaf(w0.x,h1.x,aA1); aA1=fmaf(w0.y,h1.y,aA1); aA1=fmaf(w0.z,h1.z,aA1); aA1=fmaf(w0.w,h1.w,aA1);
      aA2=fmaf(w0.x,h2.x,aA2); aA2=fmaf(w0.y,h2.y,aA2); aA2=fmaf(w0.z,h2.z,aA2); aA2=fmaf(w0.w,h2.w,aA2);
      aA3=fmaf(w0.x,h3.x,aA3); aA3=fmaf(w0.y,h3.y,aA3); aA3=fmaf(w0.z,h3.z,aA3); aA3=fmaf(w0.w,h3.w,aA3);
      aB0=fmaf(w1.x,h0.x,aB0); aB0=fmaf(w1.y,h0.y,aB0); aB0=fmaf(w1.z,h0.z,aB0); aB0=fmaf(w1.w,h0.w,aB0);
      aB1=fmaf(w1.x,h1.x,aB1); aB1=fmaf(w1.y,h1.y,aB1); aB1=fmaf(w1.z,h1.z,aB1); aB1=fmaf(w1.w,h1.w,aB1);
      aB2=fmaf(w1.x,h2.x,aB2); aB2=fmaf(w1.y,h2.y,aB2); aB2=fmaf(w1.z,h2.z,aB2); aB2=fmaf(w1.w,h2.w,aB2);
      aB3=fmaf(w1.x,h3.x,aB3); aB3=fmaf(w1.y,h3.y,aB3); aB3=fmaf(w1.z,h3.z,aB3); aB3=fmaf(w1.w,h3.w,aB3);
    }
    {
      float* sp = SbA + (size_t)b0*2048 + cA;
      sp[0]      = aA0;  sp[8]      = aB0;
      sp[2048]   = aA1;  sp[2048+8] = aB1;
      sp[4096]   = aA2;  sp[4096+8] = aB2;
      sp[6144]   = aA3;  sp[6144+8] = aB3;
    }
    grid_barrier(bar, ++ep, grp);            // S complete, globally visible

    // ======== Phase B: predictor + GRU pointwise for (dir, b) ========
    const int ts = dir ? (T_STEPS-1-t) : t;
    const float s_r1 = Sb2[j1],      s_r2 = Sb2[j2];
    const float s_z1 = Sb2[512+j1],  s_z2 = Sb2[512+j2];
    const float s_n1 = Sb2[1024+j1], s_n2 = Sb2[1024+j2];
    const float sp1  = Sb2[1536+j1], sp2  = Sb2[1536+j2];

    // predictor scalar: tanh( relu(S_p + pb1) . pw2 + pb2 )
    {
      float u1 = sp1 + pb11; u1 = u1 > 0.f ? u1 : 0.f;
      float u2 = sp2 + pb12; u2 = u2 > 0.f ? u2 : 0.f;
      float v = fmaf(u1, pw21, u2*pw22);
      #pragma unroll
      for(int off=32; off; off>>=1) v += __shfl_xor(v, off, 64);
      if((tid & 63)==0) red[tid>>6] = v;
    }
    __syncthreads();
    if(tid==0){
      const size_t idx = (size_t)b*T_STEPS + ts;
      bool mfl;
      if(mcode==1)      mfl = mk[idx] != 0;
      else if(mcode==2) mfl = ((const unsigned short*)mk)[idx] != 0;
      else              mfl = ((const unsigned int*)mk)[idx]  != 0;
      const float xraw = ldw(x + idx);
      const float xp = tanhf(red[0]+red[1]+red[2]+red[3] + pb2s);
      xsh[0] = mfl ? xp : xraw;
    }
    __syncthreads();
    const float xin = xsh[0];

    // GRU gates for this thread's two h indices (all constants in registers)
    const float r1  = 1.f/(1.f+__expf(-(fmaf(xin, wi_r1, bi_r1) + s_r1 + bh_r1)));
    const float z1  = 1.f/(1.f+__expf(-(fmaf(xin, wi_z1, bi_z1) + s_z1 + bh_z1)));
    const float n1  = tanhf(fmaf(r1, s_n1 + bh_n1, fmaf(xin, wi_n1, bi_n1)));
    const float hn1 = (1.f-z1)*n1 + z1*hp1;

    const float r2  = 1.f/(1.f+__expf(-(fmaf(xin, wi_r2, bi_r2) + s_r2 + bh_r2)));
    const float z2  = 1.f/(1.f+__expf(-(fmaf(xin, wi_z2, bi_z2) + s_z2 + bh_z2)));
    const float n2  = tanhf(fmaf(r2, s_n2 + bh_n2, fmaf(xin, wi_n2, bi_n2)));
    const float hn2 = (1.f-z2)*n2 + z2*hp2;

    hp1 = hn1; hp2 = hn2;

    // stores: output (coalesced) + H b-major row (coalesced, no write-amp)
    {
      OT* op = out + ((size_t)b*T_STEPS + ts)*(2*H_DIM) + (size_t)dir*H_DIM;
      stw(op + j1, hn1); stw(op + j2, hn2);
      float* hrow = H_B + ((size_t)dir*128 + b)*512;
      hrow[j1] = hn1; hrow[j2] = hn2;
    }
    grid_barrier(bar, ++ep, grp);            // h_t visible for next phase A
  }
}

__global__ __launch_bounds__(256, 1)
void rnn_kernel(const void* i0,const void* i1,const void* i2,const void* i3,
                const void* i4,const void* i5,const void* i6,const void* i7,
                const void* i8,const void* i9,const void* i10,const void* i11,
                const void* i12,const void* i13, int* codes, void* out, float* ws)
{
  __shared__ float wsl[16*516];              // 33.0 KB weight slice (padded)
  __shared__ float red[4];
  __shared__ float xsh[1];

  float* H_B = ws;                           // [2][128][512] = 512 KB
  float* S   = ws + 2*128*512;               // [2][128][2048] = 2 MB
  int*   bar = codes + 256;                  // barrier tree (probe-zeroed)

  if(codes[1]==0)
    body<__hip_bfloat16,__hip_bfloat16>(i0,i1,i2,i3,i4,i5,i6,i7,i8,i9,i10,i11,i12,i13,
        codes[0], (__hip_bfloat16*)out, H_B, S, bar, wsl, red, xsh);
  else
    body<float,float>(i0,i1,i2,i3,i4,i5,i6,i7,i8,i9,i10,i11,i12,i13,
        codes[0], (float*)out, H_B, S, bar, wsl, red, xsh);
}

extern "C" void kernel_launch(void* const* d_in, const int* in_sizes, int n_in,
                              void* d_out, int out_size, void* d_ws, size_t ws_size,
                              hipStream_t stream)
{
  (void)in_sizes; (void)n_in; (void)out_size; (void)ws_size;
  int*   codes = (int*)d_ws;
  float* ws    = (float*)((char*)d_ws + 8192);   // data area after 8 KB header
  probe_kernel<<<1, 256, 0, stream>>>((const unsigned int*)d_in[1],
                                      (const unsigned int*)d_in[2], codes);
  rnn_kernel<<<NBLK, 256, 0, stream>>>(d_in[0],d_in[1],d_in[2],d_in[3],d_in[4],
                                       d_in[5],d_in[6],d_in[7],d_in[8],d_in[9],
                                       d_in[10],d_in[11],d_in[12],d_in[13],
                                       codes, d_out, ws);
}